// Round 3
// baseline (135.630 us; speedup 1.0000x reference)
//
#include <hip/hip_runtime.h>
#include <hip/hip_bf16.h>
#include <hip/hip_cooperative_groups.h>

namespace cg = cooperative_groups;

#define B_  8
#define CI_ 32
#define CO_ 64
#define F_  4
#define H_  64
#define W_  64

// Single cooperative kernel, grid = B*CO = 512 blocks x 256 threads
// (2 blocks/CU on 256 CUs — co-resident at this register/LDS footprint).
//
// Phase 1 (blocks 0..255, one per (b,i)):
//   iv[b,i]  = dx^2 * sum_{h,w} wgt * v[b,i,h,w]
//   T[b,i,d] = dx^2 * sum_{h,w} wgt * vc[h,w,d] * v[b,i,h,w]
//   (wgt = trapezoid weights: 0.5 on boundary rows/cols)
// grid.sync()
// Phase 2 (block j = b*CO+o):
//   Sx0 = sum_{f,i} Wx[f,o,i,0]*iv[b,i]
//   Sx1 = sum_{f,i} Wx[f,o,i,1]*iv[b,i]
//   C   = sum_{f,i,d} Wy[f,o,i,d]*T[b,i,d]
//   out[b,o,h,w] = tc[h,w,0]*Sx0 + tc[h,w,1]*Sx1 + C   (float4 stores)
__global__ __launch_bounds__(256) void k_fused(
    const float* __restrict__ v, const float* __restrict__ vc,
    const float* __restrict__ tc, const float* __restrict__ Wx,
    const float* __restrict__ Wy, float* __restrict__ iv,
    float* __restrict__ T, float* __restrict__ out) {
  cg::grid_group grid = cg::this_grid();
  const int blk = blockIdx.x;
  const int tid = threadIdx.x;
  const int wave = tid >> 6;
  const int lane = tid & 63;

  __shared__ float red[4][3];
  __shared__ float bc[3];

  // ---------------- Phase 1: per-(b,i) quadrature reduction ----------------
  if (blk < B_ * CI_) {
    const float* vp = v + (size_t)blk * (H_ * W_);
    float s0 = 0.f, s1 = 0.f, s2 = 0.f;
    for (int p = tid; p < H_ * W_; p += 256) {
      int h = p >> 6;
      int w = p & 63;
      float wgt = ((h == 0 || h == H_ - 1) ? 0.5f : 1.0f) *
                  ((w == 0 || w == W_ - 1) ? 0.5f : 1.0f);
      float val = vp[p] * wgt;
      s0 += val;
      s1 += val * vc[2 * p];
      s2 += val * vc[2 * p + 1];
    }
    for (int off = 32; off > 0; off >>= 1) {
      s0 += __shfl_down(s0, off, 64);
      s1 += __shfl_down(s1, off, 64);
      s2 += __shfl_down(s2, off, 64);
    }
    if (lane == 0) {
      red[wave][0] = s0; red[wave][1] = s1; red[wave][2] = s2;
    }
    __syncthreads();
    if (tid == 0) {
      float t0 = red[0][0] + red[1][0] + red[2][0] + red[3][0];
      float t1 = red[0][1] + red[1][1] + red[2][1] + red[3][1];
      float t2 = red[0][2] + red[1][2] + red[2][2] + red[3][2];
      float dx = vc[2] - vc[0];     // v_coords[0,1,0] - v_coords[0,0,0]
      float sc = dx * dx;
      iv[blk]        = t0 * sc;
      T[2 * blk]     = t1 * sc;
      T[2 * blk + 1] = t2 * sc;
      __threadfence();              // device-scope visibility before barrier
    }
  }

  grid.sync();

  // ---------------- Phase 2: coefficients + plane write --------------------
  const int bo = blk;               // b*CO + o
  const int b  = bo >> 6;           // CO = 64
  const int o  = bo & 63;

  float sx0 = 0.f, sx1 = 0.f, c = 0.f;
  if (tid < CI_ * F_) {             // 128 active (i,f) terms
    int i = tid & (CI_ - 1);
    int f = tid >> 5;
    float ivbi = iv[b * CI_ + i];
    float t0 = T[(b * CI_ + i) * 2];
    float t1 = T[(b * CI_ + i) * 2 + 1];
    int base = ((f * CO_ + o) * CI_ + i) * 2;
    float2 wx = *(const float2*)(Wx + base);
    float2 wy = *(const float2*)(Wy + base);
    sx0 = wx.x * ivbi;
    sx1 = wx.y * ivbi;
    c   = wy.x * t0 + wy.y * t1;
  }
  for (int off = 32; off > 0; off >>= 1) {
    sx0 += __shfl_down(sx0, off, 64);
    sx1 += __shfl_down(sx1, off, 64);
    c   += __shfl_down(c,   off, 64);
  }
  __syncthreads();                  // red[] reuse: phase-1 reads are done
  if (wave < 2 && lane == 0) {
    red[wave][0] = sx0; red[wave][1] = sx1; red[wave][2] = c;
  }
  __syncthreads();
  if (tid == 0) {
    bc[0] = red[0][0] + red[1][0];
    bc[1] = red[0][1] + red[1][1];
    bc[2] = red[0][2] + red[1][2];
  }
  __syncthreads();
  const float SX0 = bc[0], SX1 = bc[1], C = bc[2];

  // write this (b,o)'s full 64x64 plane: 1024 float4, 4 per thread
  float4* outp = (float4*)out + (size_t)bo * 1024;
#pragma unroll
  for (int r = 0; r < 4; ++r) {
    int p4 = r * 256 + tid;         // 0..1023
    int h  = p4 >> 4;               // W/4 = 16 float4 per row
    int w4 = p4 & 15;
    const float4* tcp = (const float4*)(tc + (size_t)(h * W_ + w4 * 4) * 2);
    float4 t0v = tcp[0];            // gx0, gy0, gx1, gy1
    float4 t1v = tcp[1];            // gx2, gy2, gx3, gy3
    float4 rr;
    rr.x = t0v.x * SX0 + t0v.y * SX1 + C;
    rr.y = t0v.z * SX0 + t0v.w * SX1 + C;
    rr.z = t1v.x * SX0 + t1v.y * SX1 + C;
    rr.w = t1v.z * SX0 + t1v.w * SX1 + C;
    outp[p4] = rr;
  }
}

extern "C" void kernel_launch(void* const* d_in, const int* in_sizes, int n_in,
                              void* d_out, int out_size, void* d_ws, size_t ws_size,
                              hipStream_t stream) {
  const float* v  = (const float*)d_in[0];   // [B,CI,H,W]
  const float* vc = (const float*)d_in[1];   // [H,W,2]
  const float* tc = (const float*)d_in[2];   // [H,W,2]
  const float* Wx = (const float*)d_in[3];   // [F,CO,CI,2]
  const float* Wy = (const float*)d_in[4];   // [F,CO,CI,2]
  float* out = (float*)d_out;                // [B,CO,H,W]

  // workspace layout (floats): iv[256] | T[512]
  float* iv = (float*)d_ws;
  float* T  = iv + B_ * CI_;

  void* args[] = {(void*)&v, (void*)&vc, (void*)&tc, (void*)&Wx,
                  (void*)&Wy, (void*)&iv, (void*)&T, (void*)&out};
  hipLaunchCooperativeKernel((const void*)k_fused, dim3(B_ * CO_), dim3(256),
                             args, 0, stream);
}

// Round 4
// 75.647 us; speedup vs baseline: 1.7929x; 1.7929x over previous
//
#include <hip/hip_runtime.h>
#include <hip/hip_bf16.h>

#define B_  8
#define CI_ 32
#define CO_ 64
#define F_  4
#define H_  64
#define W_  64

// Single regular launch, 256 blocks x 256 threads (1 block/CU), no grid sync.
// Block blk = (b, opair): b = blk>>5, planes o0 = (blk&31)*2 and o0+1.
//
// Phase A (redundant per block, order-independent): reduce v[b,:,:,:] (512 KB,
// L2-hot) into iv[i], T[i][2]:
//   iv[i]  = dx^2 * sum_{h,w} wgt(h,w) * v[b,i,h,w]
//   T[i,d] = dx^2 * sum_{h,w} wgt(h,w) * vc[h,w,d] * v[b,i,h,w]
// wgt = trapezoid weights (0.5 at boundary rows/cols). 8 threads per channel,
// weights factored: per-col (wgtW, wgtW*cx) premultiplied, per-row (wgtH, cy)
// applied to row partial sums.
//
// Phase B: Sx0/Sx1/C per plane:
//   Sx_d = sum_{f,i} Wx[f,o,i,d]*iv[i],  C = sum_{f,i,d} Wy[f,o,i,d]*T[i,d]
// Phase C: out[b,o,h,w] = tc[h,w,0]*Sx0 + tc[h,w,1]*Sx1 + C  (float4 stores).
__global__ __launch_bounds__(256) void k_all(
    const float* __restrict__ v, const float* __restrict__ vc,
    const float* __restrict__ tc, const float* __restrict__ Wx,
    const float* __restrict__ Wy, float* __restrict__ out) {
  const int blk = blockIdx.x;
  const int tid = threadIdx.x;
  const int b   = blk >> 5;
  const int o0  = (blk & 31) * 2;

  __shared__ float ivT[CI_][3];   // stride 3 : conflict-free mod 32
  __shared__ float red[4][3];
  __shared__ float bc[2][3];

  // ---------------- Phase A ----------------
  const int i   = tid >> 3;       // channel 0..31
  const int sub = tid & 7;        // 8 threads/channel

  // column factors for this thread's 8 scalar cols: w = sub*4+j, sub*4+32+j
#define GW_(w) ((((w) == 0) || ((w) == W_ - 1)) ? 0.5f : 1.0f)
  const int w0 = sub * 4;
  const int w1 = sub * 4 + 32;
  const float4 wg0 = make_float4(GW_(w0), GW_(w0 + 1), GW_(w0 + 2), GW_(w0 + 3));
  const float4 wg1 = make_float4(GW_(w1), GW_(w1 + 1), GW_(w1 + 2), GW_(w1 + 3));
  const float4 wc0 = make_float4(wg0.x * vc[2 * w0],       wg0.y * vc[2 * (w0 + 1)],
                                 wg0.z * vc[2 * (w0 + 2)], wg0.w * vc[2 * (w0 + 3)]);
  const float4 wc1 = make_float4(wg1.x * vc[2 * w1],       wg1.y * vc[2 * (w1 + 1)],
                                 wg1.z * vc[2 * (w1 + 2)], wg1.w * vc[2 * (w1 + 3)]);

  const float4* vrow = (const float4*)(v + (size_t)(b * CI_ + i) * (H_ * W_));
  float s0 = 0.f, s1 = 0.f, s2 = 0.f;
#pragma unroll 4
  for (int h = 0; h < H_; ++h) {
    float4 a  = vrow[h * 16 + sub];
    float4 bq = vrow[h * 16 + sub + 8];
    float rs0 = a.x * wg0.x + a.y * wg0.y + a.z * wg0.z + a.w * wg0.w
              + bq.x * wg1.x + bq.y * wg1.y + bq.z * wg1.z + bq.w * wg1.w;
    float rs1 = a.x * wc0.x + a.y * wc0.y + a.z * wc0.z + a.w * wc0.w
              + bq.x * wc1.x + bq.y * wc1.y + bq.z * wc1.z + bq.w * wc1.w;
    float wh = ((h == 0) || (h == H_ - 1)) ? 0.5f : 1.0f;
    float cy = vc[h * (W_ * 2) + 1];
    s0 += wh * rs0;
    s1 += wh * rs1;
    s2 += (wh * cy) * rs0;
  }
  // reduce over the 8 sub-threads (adjacent lanes within the wave)
  for (int m = 1; m < 8; m <<= 1) {
    s0 += __shfl_xor(s0, m, 64);
    s1 += __shfl_xor(s1, m, 64);
    s2 += __shfl_xor(s2, m, 64);
  }
  if (sub == 0) {
    float dx = vc[2] - vc[0];     // v_coords[0,1,0] - v_coords[0,0,0]
    float sc = dx * dx;
    ivT[i][0] = s0 * sc;
    ivT[i][1] = s1 * sc;
    ivT[i][2] = s2 * sc;
  }
  __syncthreads();

  // ---------------- Phase B ----------------
  // waves 0,1 -> plane o0 (f = 0,1 / 2,3); waves 2,3 -> plane o0+1
  {
    const int half = tid >> 7;
    const int o    = o0 + half;
    const int ii   = tid & 31;
    const int f    = (tid >> 5) & 3;
    float ivi = ivT[ii][0];
    float t0  = ivT[ii][1];
    float t1  = ivT[ii][2];
    int base = ((f * CO_ + o) * CI_ + ii) * 2;
    float2 wx = *(const float2*)(Wx + base);
    float2 wy = *(const float2*)(Wy + base);
    float sx0 = wx.x * ivi;
    float sx1 = wx.y * ivi;
    float c   = wy.x * t0 + wy.y * t1;
    for (int off = 32; off > 0; off >>= 1) {
      sx0 += __shfl_down(sx0, off, 64);
      sx1 += __shfl_down(sx1, off, 64);
      c   += __shfl_down(c,   off, 64);
    }
    const int wave = tid >> 6;
    if ((tid & 63) == 0) {
      red[wave][0] = sx0; red[wave][1] = sx1; red[wave][2] = c;
    }
  }
  __syncthreads();
  if (tid < 2) {
    bc[tid][0] = red[2 * tid][0] + red[2 * tid + 1][0];
    bc[tid][1] = red[2 * tid][1] + red[2 * tid + 1][1];
    bc[tid][2] = red[2 * tid][2] + red[2 * tid + 1][2];
  }
  __syncthreads();

  // ---------------- Phase C ----------------
  const float A0 = bc[0][0], A1 = bc[0][1], Ac = bc[0][2];
  const float B0 = bc[1][0], B1 = bc[1][1], Bc = bc[1][2];
  float4* out0 = (float4*)out + (size_t)(b * CO_ + o0) * 1024;
  float4* out1 = out0 + 1024;
#pragma unroll
  for (int r = 0; r < 4; ++r) {
    int p4 = r * 256 + tid;       // 0..1023
    int h  = p4 >> 4;             // 16 float4 per row
    int w4 = p4 & 15;
    const float4* tcp = (const float4*)(tc + (size_t)(h * W_ + w4 * 4) * 2);
    float4 t0v = tcp[0];          // gx0, gy0, gx1, gy1
    float4 t1v = tcp[1];          // gx2, gy2, gx3, gy3
    float4 r0, r1;
    r0.x = t0v.x * A0 + t0v.y * A1 + Ac;
    r0.y = t0v.z * A0 + t0v.w * A1 + Ac;
    r0.z = t1v.x * A0 + t1v.y * A1 + Ac;
    r0.w = t1v.z * A0 + t1v.w * A1 + Ac;
    r1.x = t0v.x * B0 + t0v.y * B1 + Bc;
    r1.y = t0v.z * B0 + t0v.w * B1 + Bc;
    r1.z = t1v.x * B0 + t1v.w * 0.f + t1v.y * B1 + Bc;  // placeholder fixed below
    r1.w = t1v.z * B0 + t1v.w * B1 + Bc;
    r1.z = t1v.x * B0 + t1v.y * B1 + Bc;
    out0[p4] = r0;
    out1[p4] = r1;
  }
}

extern "C" void kernel_launch(void* const* d_in, const int* in_sizes, int n_in,
                              void* d_out, int out_size, void* d_ws, size_t ws_size,
                              hipStream_t stream) {
  const float* v  = (const float*)d_in[0];   // [B,CI,H,W]
  const float* vc = (const float*)d_in[1];   // [H,W,2]
  const float* tc = (const float*)d_in[2];   // [H,W,2]
  const float* Wx = (const float*)d_in[3];   // [F,CO,CI,2]
  const float* Wy = (const float*)d_in[4];   // [F,CO,CI,2]
  float* out = (float*)d_out;                // [B,CO,H,W]

  k_all<<<B_ * (CO_ / 2), 256, 0, stream>>>(v, vc, tc, Wx, Wy, out);
}

// Round 5
// 74.219 us; speedup vs baseline: 1.8274x; 1.0192x over previous
//
#include <hip/hip_runtime.h>
#include <hip/hip_bf16.h>

#define B_  8
#define CI_ 32
#define CO_ 64
#define F_  4
#define H_  64
#define W_  64

// Single regular launch, 256 blocks x 1024 threads (16 waves/CU), no grid sync.
// Block blk = (b, opair): b = blk>>5, planes o0 = (blk&31)*2 and o0+1.
//
// Phase A (redundant per block, order-independent): reduce v[b,:,:,:] (512 KB,
// L2-hot) into iv[i], T[i][2]:
//   iv[i]  = dx^2 * sum_{h,w} wgt(h,w) * v[b,i,h,w]
//   T[i,d] = dx^2 * sum_{h,w} wgt(h,w) * vc[h,w,d] * v[b,i,h,w]
// 32 threads per channel, each thread: 32 INDEPENDENT float4 loads (max MLP).
// Per-thread column factors are loop-invariant: p4 = r*32+sub -> w4 = sub&15.
//
// Phase B: per plane o: Sx_d = sum_{f,i} Wx[f,o,i,d]*iv[i],
//                       C    = sum_{f,i,d} Wy[f,o,i,d]*T[i,d]
// Phase C: out[b,o,h,w] = tc[h,w,0]*Sx0 + tc[h,w,1]*Sx1 + C  (float4 stores).
__global__ __launch_bounds__(1024) void k_all(
    const float* __restrict__ v, const float* __restrict__ vc,
    const float* __restrict__ tc, const float* __restrict__ Wx,
    const float* __restrict__ Wy, float* __restrict__ out) {
  const int blk = blockIdx.x;
  const int tid = threadIdx.x;
  const int b   = blk >> 5;
  const int o0  = (blk & 31) * 2;

  __shared__ float ivT[CI_][3];   // stride 3 : conflict-free mod 32
  __shared__ float red[4][3];
  __shared__ float bc[2][3];

  // ---------------- Phase A ----------------
  const int i   = tid >> 5;       // channel 0..31
  const int sub = tid & 31;       // 32 threads/channel
  const int w4  = sub & 15;       // fixed float4-column (32 % 16 == 0)
  const int hb  = sub >> 4;       // h parity bit: h = 2r + hb

#define GW_(w) ((((w) == 0) || ((w) == W_ - 1)) ? 0.5f : 1.0f)
  const int wsc = w4 * 4;         // first scalar col
  const float4 wg = make_float4(GW_(wsc), GW_(wsc + 1), GW_(wsc + 2), GW_(wsc + 3));
  const float4 wc = make_float4(wg.x * vc[2 * wsc],       wg.y * vc[2 * (wsc + 1)],
                                wg.z * vc[2 * (wsc + 2)], wg.w * vc[2 * (wsc + 3)]);

  const float4* vrow = (const float4*)(v + (size_t)(b * CI_ + i) * (H_ * W_));
  float s0 = 0.f, s1 = 0.f, s2 = 0.f;
#pragma unroll 8
  for (int r = 0; r < 32; ++r) {
    int p4 = r * 32 + sub;        // covers 0..1023 exactly once per channel
    int h  = 2 * r + hb;
    float4 a = vrow[p4];
    float rs0 = a.x * wg.x + a.y * wg.y + a.z * wg.z + a.w * wg.w;
    float rs1 = a.x * wc.x + a.y * wc.y + a.z * wc.z + a.w * wc.w;
    float wh = ((h == 0) || (h == H_ - 1)) ? 0.5f : 1.0f;
    float cy = vc[h * (W_ * 2) + 1];
    s0 += wh * rs0;
    s1 += wh * rs1;
    s2 += (wh * cy) * rs0;
  }
  // reduce across the 32 threads of this channel (one 32-lane half-wave)
  for (int m = 1; m < 32; m <<= 1) {
    s0 += __shfl_xor(s0, m, 64);
    s1 += __shfl_xor(s1, m, 64);
    s2 += __shfl_xor(s2, m, 64);
  }
  if (sub == 0) {
    float dx = vc[2] - vc[0];     // v_coords[0,1,0] - v_coords[0,0,0]
    float sc = dx * dx;
    ivT[i][0] = s0 * sc;
    ivT[i][1] = s1 * sc;
    ivT[i][2] = s2 * sc;
  }
  __syncthreads();

  // ---------------- Phase B ----------------
  // first 256 threads: waves 0,1 -> plane o0; waves 2,3 -> plane o0+1
  if (tid < 256) {
    const int half = tid >> 7;
    const int o    = o0 + half;
    const int ii   = tid & 31;
    const int f    = (tid >> 5) & 3;
    float ivi = ivT[ii][0];
    float t0  = ivT[ii][1];
    float t1  = ivT[ii][2];
    int base = ((f * CO_ + o) * CI_ + ii) * 2;
    float2 wx = *(const float2*)(Wx + base);
    float2 wy = *(const float2*)(Wy + base);
    float sx0 = wx.x * ivi;
    float sx1 = wx.y * ivi;
    float c   = wy.x * t0 + wy.y * t1;
    for (int off = 32; off > 0; off >>= 1) {
      sx0 += __shfl_down(sx0, off, 64);
      sx1 += __shfl_down(sx1, off, 64);
      c   += __shfl_down(c,   off, 64);
    }
    const int wave = tid >> 6;
    if ((tid & 63) == 0) {
      red[wave][0] = sx0; red[wave][1] = sx1; red[wave][2] = c;
    }
  }
  __syncthreads();
  if (tid < 2) {
    bc[tid][0] = red[2 * tid][0] + red[2 * tid + 1][0];
    bc[tid][1] = red[2 * tid][1] + red[2 * tid + 1][1];
    bc[tid][2] = red[2 * tid][2] + red[2 * tid + 1][2];
  }
  __syncthreads();

  // ---------------- Phase C ----------------
  const float A0 = bc[0][0], A1 = bc[0][1], Ac = bc[0][2];
  const float B0 = bc[1][0], B1 = bc[1][1], Bc = bc[1][2];
  float4* out0 = (float4*)out + (size_t)(b * CO_ + o0) * 1024;
  float4* out1 = out0 + 1024;
  {
    int p4 = tid;                 // 0..1023, one float4 per plane per thread
    int h  = p4 >> 4;             // 16 float4 per row
    int wq = p4 & 15;
    const float4* tcp = (const float4*)(tc + (size_t)(h * W_ + wq * 4) * 2);
    float4 t0v = tcp[0];          // gx0, gy0, gx1, gy1
    float4 t1v = tcp[1];          // gx2, gy2, gx3, gy3
    float4 r0, r1;
    r0.x = t0v.x * A0 + t0v.y * A1 + Ac;
    r0.y = t0v.z * A0 + t0v.w * A1 + Ac;
    r0.z = t1v.x * A0 + t1v.y * A1 + Ac;
    r0.w = t1v.z * A0 + t1v.w * A1 + Ac;
    r1.x = t0v.x * B0 + t0v.y * B1 + Bc;
    r1.y = t0v.z * B0 + t0v.w * B1 + Bc;
    r1.z = t1v.x * B0 + t1v.y * B1 + Bc;
    r1.w = t1v.z * B0 + t1v.w * B1 + Bc;
    out0[p4] = r0;
    out1[p4] = r1;
  }
}

extern "C" void kernel_launch(void* const* d_in, const int* in_sizes, int n_in,
                              void* d_out, int out_size, void* d_ws, size_t ws_size,
                              hipStream_t stream) {
  const float* v  = (const float*)d_in[0];   // [B,CI,H,W]
  const float* vc = (const float*)d_in[1];   // [H,W,2]
  const float* tc = (const float*)d_in[2];   // [H,W,2]
  const float* Wx = (const float*)d_in[3];   // [F,CO,CI,2]
  const float* Wy = (const float*)d_in[4];   // [F,CO,CI,2]
  float* out = (float*)d_out;                // [B,CO,H,W]

  k_all<<<B_ * (CO_ / 2), 1024, 0, stream>>>(v, vc, tc, Wx, Wy, out);
}

// Round 6
// 69.176 us; speedup vs baseline: 1.9606x; 1.0729x over previous
//
#include <hip/hip_runtime.h>
#include <hip/hip_bf16.h>

#define B_  8
#define CI_ 32
#define CO_ 64
#define F_  4
#define H_  64
#define W_  64

// Kernel 1: one block per (b,i), 1024 threads, ONE float4 of v per thread
// (1024 x 16B = the full 64x64 plane). Computes
//   iv[b,i]   = dx^2 * sum_{h,w} wgt * v[b,i,h,w]
//   T[b,i,d]  = dx^2 * sum_{h,w} wgt * vc[h,w,d] * v[b,i,h,w]
// wgt = trapezoid weights (0.5 at h/w boundaries). Fully coalesced, 16
// waves/CU -> HBM-bound (~4 MB total).
__global__ __launch_bounds__(1024) void k_reduce(
    const float* __restrict__ v, const float* __restrict__ vc,
    float* __restrict__ iv, float* __restrict__ T) {
  const int bi  = blockIdx.x;        // 0 .. B*CI-1
  const int tid = threadIdx.x;       // 0 .. 1023
  const int h   = tid >> 4;          // 16 float4 per row
  const int w4  = tid & 15;

#define GW_(w) ((((w) == 0) || ((w) == W_ - 1)) ? 0.5f : 1.0f)
  const int wsc = w4 * 4;
  const float4 wg = make_float4(GW_(wsc), GW_(wsc + 1), GW_(wsc + 2), GW_(wsc + 3));
  const float cx0 = vc[2 * wsc],       cx1 = vc[2 * (wsc + 1)];
  const float cx2 = vc[2 * (wsc + 2)], cx3 = vc[2 * (wsc + 3)];
  const float cy  = vc[h * (W_ * 2) + 1];
  const float wh  = ((h == 0) || (h == H_ - 1)) ? 0.5f : 1.0f;

  float4 a = ((const float4*)(v + (size_t)bi * (H_ * W_)))[tid];

  float rs0 = a.x * wg.x + a.y * wg.y + a.z * wg.z + a.w * wg.w;
  float rs1 = a.x * wg.x * cx0 + a.y * wg.y * cx1 + a.z * wg.z * cx2 + a.w * wg.w * cx3;
  float s0 = wh * rs0;
  float s1 = wh * rs1;
  float s2 = wh * cy * rs0;

  // wave (64-lane) reduce
  for (int off = 32; off > 0; off >>= 1) {
    s0 += __shfl_down(s0, off, 64);
    s1 += __shfl_down(s1, off, 64);
    s2 += __shfl_down(s2, off, 64);
  }
  __shared__ float red[16][3];
  const int wave = tid >> 6;
  if ((tid & 63) == 0) {
    red[wave][0] = s0; red[wave][1] = s1; red[wave][2] = s2;
  }
  __syncthreads();
  if (tid < 16) {                    // all in wave 0
    float t0 = red[tid][0], t1 = red[tid][1], t2 = red[tid][2];
    for (int off = 8; off > 0; off >>= 1) {
      t0 += __shfl_down(t0, off, 64);
      t1 += __shfl_down(t1, off, 64);
      t2 += __shfl_down(t2, off, 64);
    }
    if (tid == 0) {
      float dx = vc[2] - vc[0];      // v_coords[0,1,0] - v_coords[0,0,0]
      float sc = dx * dx;
      iv[bi]        = t0 * sc;
      T[2 * bi]     = t1 * sc;
      T[2 * bi + 1] = t2 * sc;
    }
  }
}

// Kernel 2 (proven R2 version): 4 blocks per (b,o). Each block computes the 3
// affine coefficients from L2-hot iv/T/Wx/Wy, then writes its quarter plane:
//   out[b,o,h,w] = tc[h,w,0]*Sx0 + tc[h,w,1]*Sx1 + C
__global__ __launch_bounds__(256) void k_out_fused(
    const float* __restrict__ tc, const float* __restrict__ Wx,
    const float* __restrict__ Wy, const float* __restrict__ iv,
    const float* __restrict__ T, float* __restrict__ out) {
  const int blk = blockIdx.x;        // 0 .. B*CO*4 - 1
  const int tid = threadIdx.x;       // 256
  const int bo  = blk >> 2;          // (b*CO + o)
  const int b   = bo >> 6;           // CO = 64
  const int o   = bo & 63;

  float sx0 = 0.f, sx1 = 0.f, c = 0.f;
  if (tid < CI_ * F_) {              // 128 active terms
    int i = tid & (CI_ - 1);
    int f = tid >> 5;
    float ivbi = iv[b * CI_ + i];
    float t0 = T[(b * CI_ + i) * 2];
    float t1 = T[(b * CI_ + i) * 2 + 1];
    int base = ((f * CO_ + o) * CI_ + i) * 2;
    float2 wx = *(const float2*)(Wx + base);
    float2 wy = *(const float2*)(Wy + base);
    sx0 = wx.x * ivbi;
    sx1 = wx.y * ivbi;
    c   = wy.x * t0 + wy.y * t1;
  }
  for (int off = 32; off > 0; off >>= 1) {
    sx0 += __shfl_down(sx0, off, 64);
    sx1 += __shfl_down(sx1, off, 64);
    c   += __shfl_down(c,   off, 64);
  }
  __shared__ float red[2][3];
  __shared__ float bc[3];
  int wave = tid >> 6;
  int lane = tid & 63;
  if (wave < 2 && lane == 0) {
    red[wave][0] = sx0; red[wave][1] = sx1; red[wave][2] = c;
  }
  __syncthreads();
  if (tid == 0) {
    bc[0] = red[0][0] + red[1][0];
    bc[1] = red[0][1] + red[1][1];
    bc[2] = red[0][2] + red[1][2];
  }
  __syncthreads();
  const float SX0 = bc[0], SX1 = bc[1], C = bc[2];

  int p4 = (blk & 3) * 256 + tid;    // 0..1023 float4-index within (b,o)
  int h  = p4 >> 4;                  // W/4 = 16 float4 per row
  int w4 = p4 & 15;

  const float4* tcp = (const float4*)(tc + (size_t)(h * W_ + w4 * 4) * 2);
  float4 t0v = tcp[0];               // gx0, gy0, gx1, gy1
  float4 t1v = tcp[1];               // gx2, gy2, gx3, gy3

  float4 r;
  r.x = t0v.x * SX0 + t0v.y * SX1 + C;
  r.y = t0v.z * SX0 + t0v.w * SX1 + C;
  r.z = t1v.x * SX0 + t1v.y * SX1 + C;
  r.w = t1v.z * SX0 + t1v.w * SX1 + C;

  ((float4*)out)[(size_t)bo * 1024 + p4] = r;
}

extern "C" void kernel_launch(void* const* d_in, const int* in_sizes, int n_in,
                              void* d_out, int out_size, void* d_ws, size_t ws_size,
                              hipStream_t stream) {
  const float* v  = (const float*)d_in[0];   // [B,CI,H,W]
  const float* vc = (const float*)d_in[1];   // [H,W,2]
  const float* tc = (const float*)d_in[2];   // [H,W,2]
  const float* Wx = (const float*)d_in[3];   // [F,CO,CI,2]
  const float* Wy = (const float*)d_in[4];   // [F,CO,CI,2]
  float* out = (float*)d_out;                // [B,CO,H,W]

  // workspace layout (floats): iv[256] | T[512]
  float* iv = (float*)d_ws;
  float* T  = iv + B_ * CI_;

  k_reduce<<<B_ * CI_, 1024, 0, stream>>>(v, vc, iv, T);
  k_out_fused<<<B_ * CO_ * 4, 256, 0, stream>>>(tc, Wx, Wy, iv, T, out);
}